// Round 7
// baseline (334.577 us; speedup 1.0000x reference)
//
#include <hip/hip_runtime.h>
#include <stdint.h>

#define B_     2
#define N_     2048
#define QD_    1024
#define H_     16
#define DH_    64
#define INNER_ 1024
#define SCALE_ 0.125f

typedef unsigned short u16;
typedef __attribute__((ext_vector_type(8))) short bf16x8;   // 8 bf16 = 4 VGPRs
typedef __attribute__((ext_vector_type(4))) float f32x4;    // MFMA C/D frag
typedef __attribute__((ext_vector_type(4))) unsigned short u16x4;

// ---- bf16 helpers (RNE) ----
__device__ inline u16 f2bf(float f) {
    union { float f; uint32_t u; } c; c.f = f;
    uint32_t r = c.u + 0x7FFFu + ((c.u >> 16) & 1u);
    return (u16)(r >> 16);
}
__device__ inline float bf2f(u16 s) {
    union { uint32_t u; float f; } c; c.u = ((uint32_t)s) << 16;
    return c.f;
}
__device__ inline void split2(float v, u16 &h, u16 &l) {
    u16 hs = f2bf(v);
    h = hs;
    l = f2bf(v - bf2f(hs));
}

// ---- prep: split_x (blocks 0..4095) + W transposes (blocks 4096..8191) ----
__global__ __launch_bounds__(256) void prep_kernel(
    const float* __restrict__ x, u16* __restrict__ xh, u16* __restrict__ xl,
    const float* __restrict__ Wq, const float* __restrict__ Wkv, const float* __restrict__ Wo,
    u16* __restrict__ wTh, u16* __restrict__ wTl,
    u16* __restrict__ woTh, u16* __restrict__ woTl)
{
    __shared__ float t[32][33];
    const int blk = blockIdx.x, tid = threadIdx.x;
    if (blk < 4096) {
        int idx = blk * 256 + tid;
        float4 v = ((const float4*)x)[idx];
        u16x4 hv, lv; u16 h, l;
        split2(v.x, h, l); hv.x = h; lv.x = l;
        split2(v.y, h, l); hv.y = h; lv.y = l;
        split2(v.z, h, l); hv.z = h; lv.z = l;
        split2(v.w, h, l); hv.w = h; lv.w = l;
        ((u16x4*)xh)[idx] = hv;
        ((u16x4*)xl)[idx] = lv;
        return;
    }
    int local = blk - 4096;
    const float* src; u16 *dhi, *dlo; int C, bx, by;
    if (local < 1024)      { src = Wq;  dhi = wTh;                dlo = wTl;                C = 1024; by = local >> 5; bx = local & 31; }
    else if (local < 3072) { int l2 = local - 1024; src = Wkv; dhi = wTh + 1024 * 1024; dlo = wTl + 1024 * 1024; C = 2048; by = l2 >> 6; bx = l2 & 63; }
    else                   { int l2 = local - 3072; src = Wo;  dhi = woTh;               dlo = woTl;               C = 1024; by = l2 >> 5; bx = l2 & 31; }
    const int x0 = bx * 32, y0 = by * 32;
    const int tx = tid & 31, ty = tid >> 5;
    for (int yy = ty; yy < 32; yy += 8)
        t[yy][tx] = src[(size_t)(y0 + yy) * C + x0 + tx];
    __syncthreads();
    for (int i = ty; i < 32; i += 8) {
        float v = t[tx][i];                        // src[y0+tx][x0+i]
        u16 h, l; split2(v, h, l);
        size_t o = (size_t)(x0 + i) * 1024 + y0 + tx;  // dst rows = src cols; R=1024
        dhi[o] = h; dlo[o] = l;
    }
}

// ---- stage 1: GEMM x @ [Wq|Wkv] + co-scheduled bias transpose.
// Gemm blocks FIRST (0..767) for co-residency; bias blocks (768..2815) backfill.
__global__ __launch_bounds__(256) void gemm_qkv_bias(
    int mode,
    const u16* __restrict__ Ah, const u16* __restrict__ Al,
    const u16* __restrict__ Bh, const u16* __restrict__ Bl,
    u16* __restrict__ qh, u16* __restrict__ ql,
    u16* __restrict__ kb, u16* __restrict__ vT,
    const float* __restrict__ bias, const int* __restrict__ mask,
    u16* __restrict__ biasT)
{
    __shared__ __align__(16) char smem[32768];
    const int tid = threadIdx.x;

    int gid = -1, bid = -1;
    if (mode == 1) {
        if (blockIdx.x < 768) gid = blockIdx.x; else bid = blockIdx.x - 768;
    } else if (mode == 0) gid = blockIdx.x;
    else bid = blockIdx.x;

    if (bid >= 0) {
        float (*t)[65] = (float(*)[65])smem;
        const int b = bid >> 10, rest = bid & 1023;
        const int k0 = (rest & 31) * 64, q0 = (rest >> 5) * 64;
#pragma unroll
        for (int it = 0; it < 16; it++) {
            int idx = it * 256 + tid;
            int qq = idx >> 6, kk = idx & 63;
            t[qq][kk] = bias[((size_t)b * N_ + q0 + qq) * N_ + k0 + kk];
        }
        __syncthreads();
        const u16 NEG = f2bf(-1e30f);
#pragma unroll
        for (int it = 0; it < 16; it++) {
            int idx = it * 256 + tid;
            int kk = idx >> 6, qq = idx & 63;
            int mok = mask[b * N_ + k0 + kk];
            biasT[((size_t)b * N_ + k0 + kk) * N_ + q0 + qq] = mok ? f2bf(t[qq][kk]) : NEG;
        }
        return;
    }

    u16* sAh = (u16*)smem;
    u16* sAl = (u16*)(smem + 8192);
    u16* sBh = (u16*)(smem + 16384);
    u16* sBl = (u16*)(smem + 24576);
    const int wave = tid >> 6, lane = tid & 63;
    const int quad = lane >> 4, l16 = lane & 15;
    const int wm = wave >> 1, wn = wave & 1;
    const int bx = gid % 24, by = gid / 24;
    const int bm = by * 128, bn = bx * 128;
    const bool comp = (bx < 8);

    f32x4 acc[4][4];
#pragma unroll
    for (int i = 0; i < 4; i++)
#pragma unroll
        for (int j = 0; j < 4; j++) acc[i][j] = (f32x4){0.f, 0.f, 0.f, 0.f};

    const int row0 = tid >> 2, g4 = tid & 3;
    const int r1 = row0, r2 = row0 + 64;
    const int gc1 = (g4 ^ (r1 & 3)) * 8, gc2 = (g4 ^ (r2 & 3)) * 8;
    const size_t a1 = (size_t)(bm + r1) * 1024 + gc1, a2 = (size_t)(bm + r2) * 1024 + gc2;
    const size_t b1 = (size_t)(bn + r1) * 1024 + gc1, b2 = (size_t)(bn + r2) * 1024 + gc2;
    const int w1 = r1 * 32 + g4 * 8, w2 = r2 * 32 + g4 * 8;

    if (comp) {
        bf16x8 pAh0, pAh1, pAl0, pAl1, pBh0, pBh1, pBl0, pBl1;
        pAh0 = *(const bf16x8*)&Ah[a1]; pAh1 = *(const bf16x8*)&Ah[a2];
        pAl0 = *(const bf16x8*)&Al[a1]; pAl1 = *(const bf16x8*)&Al[a2];
        pBh0 = *(const bf16x8*)&Bh[b1]; pBh1 = *(const bf16x8*)&Bh[b2];
        pBl0 = *(const bf16x8*)&Bl[b1]; pBl1 = *(const bf16x8*)&Bl[b2];
        for (int k0 = 0; k0 < 1024; k0 += 32) {
            *(bf16x8*)&sAh[w1] = pAh0; *(bf16x8*)&sAh[w2] = pAh1;
            *(bf16x8*)&sAl[w1] = pAl0; *(bf16x8*)&sAl[w2] = pAl1;
            *(bf16x8*)&sBh[w1] = pBh0; *(bf16x8*)&sBh[w2] = pBh1;
            *(bf16x8*)&sBl[w1] = pBl0; *(bf16x8*)&sBl[w2] = pBl1;
            __syncthreads();
            if (k0 + 32 < 1024) {
                int kn = k0 + 32;
                pAh0 = *(const bf16x8*)&Ah[a1 + kn]; pAh1 = *(const bf16x8*)&Ah[a2 + kn];
                pAl0 = *(const bf16x8*)&Al[a1 + kn]; pAl1 = *(const bf16x8*)&Al[a2 + kn];
                pBh0 = *(const bf16x8*)&Bh[b1 + kn]; pBh1 = *(const bf16x8*)&Bh[b2 + kn];
                pBl0 = *(const bf16x8*)&Bl[b1 + kn]; pBl1 = *(const bf16x8*)&Bl[b2 + kn];
            }
            bf16x8 fah[4], fal[4], fbh[4], fbl[4];
#pragma unroll
            for (int s = 0; s < 4; s++) {
                int ra = wm * 64 + s * 16 + l16;
                int rb = wn * 64 + s * 16 + l16;
                int ca = (quad ^ (ra & 3)) * 8;
                int cb = (quad ^ (rb & 3)) * 8;
                fah[s] = *(const bf16x8*)&sAh[ra * 32 + ca];
                fal[s] = *(const bf16x8*)&sAl[ra * 32 + ca];
                fbh[s] = *(const bf16x8*)&sBh[rb * 32 + cb];
                fbl[s] = *(const bf16x8*)&sBl[rb * 32 + cb];
            }
#pragma unroll
            for (int sm = 0; sm < 4; sm++)
#pragma unroll
                for (int sn = 0; sn < 4; sn++) {
                    acc[sm][sn] = __builtin_amdgcn_mfma_f32_16x16x32_bf16(fah[sm], fbh[sn], acc[sm][sn], 0, 0, 0);
                    acc[sm][sn] = __builtin_amdgcn_mfma_f32_16x16x32_bf16(fal[sm], fbh[sn], acc[sm][sn], 0, 0, 0);
                    acc[sm][sn] = __builtin_amdgcn_mfma_f32_16x16x32_bf16(fah[sm], fbl[sn], acc[sm][sn], 0, 0, 0);
                }
            __syncthreads();
        }
    } else {
        bf16x8 pAh0, pAh1, pBh0, pBh1;
        pAh0 = *(const bf16x8*)&Ah[a1]; pAh1 = *(const bf16x8*)&Ah[a2];
        pBh0 = *(const bf16x8*)&Bh[b1]; pBh1 = *(const bf16x8*)&Bh[b2];
        for (int k0 = 0; k0 < 1024; k0 += 32) {
            *(bf16x8*)&sAh[w1] = pAh0; *(bf16x8*)&sAh[w2] = pAh1;
            *(bf16x8*)&sBh[w1] = pBh0; *(bf16x8*)&sBh[w2] = pBh1;
            __syncthreads();
            if (k0 + 32 < 1024) {
                int kn = k0 + 32;
                pAh0 = *(const bf16x8*)&Ah[a1 + kn]; pAh1 = *(const bf16x8*)&Ah[a2 + kn];
                pBh0 = *(const bf16x8*)&Bh[b1 + kn]; pBh1 = *(const bf16x8*)&Bh[b2 + kn];
            }
            bf16x8 fah[4], fbh[4];
#pragma unroll
            for (int s = 0; s < 4; s++) {
                int ra = wm * 64 + s * 16 + l16;
                int rb = wn * 64 + s * 16 + l16;
                int ca = (quad ^ (ra & 3)) * 8;
                int cb = (quad ^ (rb & 3)) * 8;
                fah[s] = *(const bf16x8*)&sAh[ra * 32 + ca];
                fbh[s] = *(const bf16x8*)&sBh[rb * 32 + cb];
            }
#pragma unroll
            for (int sm = 0; sm < 4; sm++)
#pragma unroll
                for (int sn = 0; sn < 4; sn++)
                    acc[sm][sn] = __builtin_amdgcn_mfma_f32_16x16x32_bf16(fah[sm], fbh[sn], acc[sm][sn], 0, 0, 0);
            __syncthreads();
        }
    }
#pragma unroll
    for (int sm = 0; sm < 4; sm++) {
        int rowb = bm + wm * 64 + sm * 16 + quad * 4;
        int bb = rowb >> 11, i0 = rowb & 2047;
#pragma unroll
        for (int sn = 0; sn < 4; sn++) {
            int col = bn + wn * 64 + sn * 16 + l16;
            int region = col >> 10;
            int hh = (col >> 6) & 15;
            int d = col & 63;
            if (region == 0) {
#pragma unroll
                for (int r = 0; r < 4; r++) {
                    float val = acc[sm][sn][r] * SCALE_;
                    u16 a, c; split2(val, a, c);
                    size_t o = (((size_t)(bb * H_ + hh)) * N_ + i0 + r) * DH_ + d;
                    qh[o] = a; ql[o] = c;
                }
            } else if (region == 1) {
#pragma unroll
                for (int r = 0; r < 4; r++) {
                    size_t o = (((size_t)(bb * H_ + hh)) * N_ + i0 + r) * DH_ + d;
                    kb[o] = f2bf(acc[sm][sn][r]);
                }
            } else {
                u16x4 pv;
#pragma unroll
                for (int r = 0; r < 4; r++) pv[r] = f2bf(acc[sm][sn][r]);
                *(u16x4*)&vT[(((size_t)(bb * H_ + hh)) * DH_ + d) * N_ + i0] = pv;
            }
        }
    }
}

// ---- stage 3: O(bf16) @ Wo(hi/lo) + bo -> fp32. 128x64 tiles, 512 blocks ----
__global__ __launch_bounds__(256) void gemm_out(
    const u16* __restrict__ Ab,
    const u16* __restrict__ Bh, const u16* __restrict__ Bl,
    const float* __restrict__ bo, float* __restrict__ out)
{
    __shared__ __align__(16) u16 sA[128 * 32], sBh[64 * 32], sBl[64 * 32];
    const int tid = threadIdx.x;
    const int wave = tid >> 6, lane = tid & 63;
    const int quad = lane >> 4, l16 = lane & 15;
    const int wm = wave >> 1, wn = wave & 1;
    const int bm = blockIdx.y * 128, bn = blockIdx.x * 64;

    f32x4 acc[4][2];
#pragma unroll
    for (int i = 0; i < 4; i++)
#pragma unroll
        for (int j = 0; j < 2; j++) acc[i][j] = (f32x4){0.f, 0.f, 0.f, 0.f};

    const int row0 = tid >> 2, g4 = tid & 3;
    const int r1 = row0, r2 = row0 + 64;
    const int rb0 = tid >> 2;
    const int gc1 = (g4 ^ (r1 & 3)) * 8, gc2 = (g4 ^ (r2 & 3)) * 8;
    const size_t a1 = (size_t)(bm + r1) * 1024 + gc1, a2 = (size_t)(bm + r2) * 1024 + gc2;
    const size_t bgo = (size_t)(bn + rb0) * 1024 + gc1;
    const int w1 = r1 * 32 + g4 * 8, w2 = r2 * 32 + g4 * 8;
    const int wb = rb0 * 32 + g4 * 8;

    bf16x8 pA0, pA1, pBh0, pBl0;
    pA0 = *(const bf16x8*)&Ab[a1]; pA1 = *(const bf16x8*)&Ab[a2];
    pBh0 = *(const bf16x8*)&Bh[bgo]; pBl0 = *(const bf16x8*)&Bl[bgo];

    for (int k0 = 0; k0 < 1024; k0 += 32) {
        *(bf16x8*)&sA[w1] = pA0;  *(bf16x8*)&sA[w2] = pA1;
        *(bf16x8*)&sBh[wb] = pBh0; *(bf16x8*)&sBl[wb] = pBl0;
        __syncthreads();
        if (k0 + 32 < 1024) {
            int kn = k0 + 32;
            pA0 = *(const bf16x8*)&Ab[a1 + kn]; pA1 = *(const bf16x8*)&Ab[a2 + kn];
            pBh0 = *(const bf16x8*)&Bh[bgo + kn]; pBl0 = *(const bf16x8*)&Bl[bgo + kn];
        }
        bf16x8 fa[4], fbh[2], fbl[2];
#pragma unroll
        for (int s = 0; s < 4; s++) {
            int ra = wm * 64 + s * 16 + l16;
            int ca = (quad ^ (ra & 3)) * 8;
            fa[s] = *(const bf16x8*)&sA[ra * 32 + ca];
        }
#pragma unroll
        for (int s = 0; s < 2; s++) {
            int rb = wn * 32 + s * 16 + l16;
            int cb = (quad ^ (rb & 3)) * 8;
            fbh[s] = *(const bf16x8*)&sBh[rb * 32 + cb];
            fbl[s] = *(const bf16x8*)&sBl[rb * 32 + cb];
        }
#pragma unroll
        for (int sm = 0; sm < 4; sm++)
#pragma unroll
            for (int sn = 0; sn < 2; sn++) {
                acc[sm][sn] = __builtin_amdgcn_mfma_f32_16x16x32_bf16(fa[sm], fbh[sn], acc[sm][sn], 0, 0, 0);
                acc[sm][sn] = __builtin_amdgcn_mfma_f32_16x16x32_bf16(fa[sm], fbl[sn], acc[sm][sn], 0, 0, 0);
            }
        __syncthreads();
    }
#pragma unroll
    for (int sm = 0; sm < 4; sm++) {
        int rowb = bm + wm * 64 + sm * 16 + quad * 4;
#pragma unroll
        for (int sn = 0; sn < 2; sn++) {
            int col = bn + wn * 32 + sn * 16 + l16;
            float bv = bo[col];
#pragma unroll
            for (int r = 0; r < 4; r++)
                out[(size_t)(rowb + r) * 1024 + col] = acc[sm][sn][r] + bv;
        }
    }
}

// ---- stage 2: flash attention; 2x2 wave grid (wq: 32 queries, wk: 64 keys) ----
// LDS 53248 -> 3 blocks/CU (12 waves/CU, 3/SIMD). Bias: direct register
// double-buffered prefetch (no LDS staging; zero cross-wave reuse anyway).
#define LDK 72    // sK  [128 keys][64 d]
#define LDV 136   // sVt [64 d][128 keys]
#define LDP 68    // sP  [4 waves][32 q][64 keys]

__global__ __launch_bounds__(256, 3) void attn_kernel(
    const u16* __restrict__ qh, const u16* __restrict__ ql,
    const u16* __restrict__ kb, const u16* __restrict__ vT,
    const u16* __restrict__ biasT, u16* __restrict__ ob)
{
    __shared__ __align__(16) char smem[53248];
    u16* sK  = (u16*)smem;               // 128*72*2  = 18432
    u16* sVt = (u16*)(smem + 18432);     // 64*136*2  = 17408
    u16* sP  = (u16*)(smem + 35840);     // 4*32*68*2 = 17408
    float* rO = (float*)smem;            // epilogue alias [2 wk][64 q][68] f32 = 34816
    float* rL = (float*)(smem + 34816);  // [2][64] f32

    const int bh = blockIdx.x, b = bh >> 4, h = bh & 15;
    const int qbase = blockIdx.y * 64;
    const int tid = threadIdx.x, wave = tid >> 6, lane = tid & 63;
    const int quad = lane >> 4, l16 = lane & 15;
    const int wq = wave >> 1, wk = wave & 1;

    // Q A-frags: 32 queries (2 m-tiles), pre-scaled by SCALE in gemm_qkv
    bf16x8 aqh_[2][2], aql_[2][2];
#pragma unroll
    for (int m = 0; m < 2; m++) {
        size_t qo = ((size_t)bh * N_ + qbase + wq * 32 + m * 16 + l16) * DH_ + quad * 8;
#pragma unroll
        for (int s = 0; s < 2; s++) {
            aqh_[m][s] = *(const bf16x8*)&qh[qo + s * 32];
            aql_[m][s] = *(const bf16x8*)&ql[qo + s * 32];
        }
    }
    f32x4 Oacc[2][4], lacc[2];
#pragma unroll
    for (int m = 0; m < 2; m++) {
        lacc[m] = (f32x4){0.f, 0.f, 0.f, 0.f};
#pragma unroll
        for (int nd = 0; nd < 4; nd++) Oacc[m][nd] = (f32x4){0.f, 0.f, 0.f, 0.f};
    }
    bf16x8 ones;
#pragma unroll
    for (int i = 0; i < 8; i++) ones[i] = (short)0x3F80;

    const int rK = tid >> 3, cK = (tid & 7) * 8;    // K staging: rows +it*32
    const int rV = tid >> 4, cV = (tid & 15) * 8;   // V staging: rows +it*16
    const size_t kgbase = (size_t)bh * N_ * DH_;
    const size_t vgbase = (size_t)bh * DH_ * N_;
    const size_t brow0  = (size_t)b * N_;                        // bias key-row base
    const int    bcol   = qbase + wq * 32 + quad * 4;            // bias q-col (+m*16)

    bf16x8 pK[4], pV[4];
    u16x4 pB[2][4];
#pragma unroll
    for (int it = 0; it < 4; it++) {
        pK[it] = *(const bf16x8*)&kb[kgbase + (size_t)(rK + it * 32) * DH_ + cK];
        pV[it] = *(const bf16x8*)&vT[vgbase + (size_t)(rV + it * 16) * N_ + cV];
    }
#pragma unroll
    for (int m = 0; m < 2; m++)
#pragma unroll
        for (int n = 0; n < 4; n++)
            pB[m][n] = *(const u16x4*)&biasT[(brow0 + wk * 64 + n * 16 + l16) * N_ + bcol + m * 16];

    for (int jt = 0; jt < 16; jt++) {
        // commit staged K/V tile
#pragma unroll
        for (int it = 0; it < 4; it++) {
            *(bf16x8*)&sK[(rK + it * 32) * LDK + cK] = pK[it];
            *(bf16x8*)&sVt[(rV + it * 16) * LDV + cV] = pV[it];
        }
        __syncthreads();
        // prefetch next tile's K/V and bias (consumed next iteration)
        u16x4 pBn[2][4];
        {
            int j0n = ((jt + 1) & 15) * 128;
#pragma unroll
            for (int it = 0; it < 4; it++) {
                pK[it] = *(const bf16x8*)&kb[kgbase + (size_t)(j0n + rK + it * 32) * DH_ + cK];
                pV[it] = *(const bf16x8*)&vT[vgbase + (size_t)(rV + it * 16) * N_ + j0n + cV];
            }
#pragma unroll
            for (int m = 0; m < 2; m++)
#pragma unroll
                for (int n = 0; n < 4; n++)
                    pBn[m][n] = *(const u16x4*)&biasT[(brow0 + j0n + wk * 64 + n * 16 + l16) * N_ + bcol + m * 16];
        }
        // S = Q K^T + bias, exp, P -> LDS (per-wave region)
        u16* pw = sP + wave * 32 * LDP;
#pragma unroll
        for (int m = 0; m < 2; m++) {
            f32x4 S[4];
#pragma unroll
            for (int n = 0; n < 4; n++) {
                f32x4 a = (f32x4){0.f, 0.f, 0.f, 0.f};
#pragma unroll
                for (int s = 0; s < 2; s++) {
                    bf16x8 kf = *(const bf16x8*)&sK[(wk * 64 + n * 16 + l16) * LDK + s * 32 + quad * 8];
                    a = __builtin_amdgcn_mfma_f32_16x16x32_bf16(aqh_[m][s], kf, a, 0, 0, 0);
                    a = __builtin_amdgcn_mfma_f32_16x16x32_bf16(aql_[m][s], kf, a, 0, 0, 0);
                }
                S[n] = a;
            }
#pragma unroll
            for (int n = 0; n < 4; n++) {
                u16x4 bv = pB[m][n];
#pragma unroll
                for (int r = 0; r < 4; r++)
                    S[n][r] = __expf(S[n][r] + bf2f(bv[r]));
            }
#pragma unroll
            for (int n = 0; n < 4; n++)
#pragma unroll
                for (int r = 0; r < 4; r++)
                    pw[(m * 16 + quad * 4 + r) * LDP + n * 16 + l16] = f2bf(S[n][r]);
        }
        // PV + l (pa frags shared across nd; vf shared across m)
        bf16x8 pa[2][2];
#pragma unroll
        for (int m = 0; m < 2; m++)
#pragma unroll
            for (int s = 0; s < 2; s++) {
                pa[m][s] = *(const bf16x8*)&pw[(m * 16 + l16) * LDP + s * 32 + quad * 8];
                lacc[m] = __builtin_amdgcn_mfma_f32_16x16x32_bf16(pa[m][s], ones, lacc[m], 0, 0, 0);
            }
#pragma unroll
        for (int s = 0; s < 2; s++)
#pragma unroll
            for (int nd = 0; nd < 4; nd++) {
                bf16x8 vf = *(const bf16x8*)&sVt[(nd * 16 + l16) * LDV + wk * 64 + s * 32 + quad * 8];
#pragma unroll
                for (int m = 0; m < 2; m++)
                    Oacc[m][nd] = __builtin_amdgcn_mfma_f32_16x16x32_bf16(pa[m][s], vf, Oacc[m][nd], 0, 0, 0);
            }
#pragma unroll
        for (int m = 0; m < 2; m++)
#pragma unroll
            for (int n = 0; n < 4; n++) pB[m][n] = pBn[m][n];
        __syncthreads();
    }

    // cross-wk reduction of O and l partials through LDS
#pragma unroll
    for (int m = 0; m < 2; m++) {
        int qloc = wq * 32 + m * 16 + quad * 4;
#pragma unroll
        for (int nd = 0; nd < 4; nd++)
#pragma unroll
            for (int r = 0; r < 4; r++)
                rO[(wk * 64 + qloc + r) * 68 + nd * 16 + l16] = Oacc[m][nd][r];
        if (l16 == 0) {
#pragma unroll
            for (int r = 0; r < 4; r++)
                rL[wk * 64 + qloc + r] = lacc[m][r];
        }
    }
    __syncthreads();
    {
        const int q = tid >> 2, dg = (tid & 3) * 16;
        float l = rL[q] + rL[64 + q];
        float inv = 1.f / l;
        f32x4 s[4];
#pragma unroll
        for (int i4 = 0; i4 < 4; i4++) {
            s[i4] = *(const f32x4*)&rO[(size_t)q * 68 + dg + i4 * 4];
            f32x4 v = *(const f32x4*)&rO[(size_t)(64 + q) * 68 + dg + i4 * 4];
            s[i4] += v;
        }
        size_t obase = ((size_t)b * N_ + qbase + q) * INNER_ + h * 64 + dg;
#pragma unroll
        for (int i4 = 0; i4 < 4; i4++) {
            u16x4 o4;
#pragma unroll
            for (int r = 0; r < 4; r++) o4[r] = f2bf(s[i4][r] * inv);
            *(u16x4*)&ob[obase + i4 * 4] = o4;
        }
    }
}

extern "C" void kernel_launch(void* const* d_in, const int* in_sizes, int n_in,
                              void* d_out, int out_size, void* d_ws, size_t ws_size,
                              hipStream_t stream)
{
    const float* x    = (const float*)d_in[0];
    const float* bias = (const float*)d_in[1];
    const int*   mask = (const int*)d_in[2];
    const float* Wq   = (const float*)d_in[3];
    const float* Wkv  = (const float*)d_in[4];
    const float* Wo   = (const float*)d_in[5];
    const float* bo   = (const float*)d_in[6];
    float* out = (float*)d_out;

    char* w = (char*)d_ws;
    const size_t MB = 1024 * 1024;
    u16* q_h   = (u16*)(w);             //  0..8   [32][2048][64]
    u16* q_l   = (u16*)(w + 8 * MB);
    u16* k_b   = (u16*)(w + 16 * MB);
    u16* v_T   = (u16*)(w + 24 * MB);   // [32][64][2048]
    u16* xs_h  = (u16*)(w + 32 * MB);
    u16* xs_l  = (u16*)(w + 40 * MB);
    u16* wT_h  = (u16*)(w + 48 * MB);   // [3072][1024]
    u16* wT_l  = (u16*)(w + 54 * MB);
    u16* woT_h = (u16*)(w + 60 * MB);
    u16* woT_l = (u16*)(w + 62 * MB);
    u16* o_b   = (u16*)(w + 64 * MB);   // [2][2048][1024]

    const size_t biasT_bytes = (size_t)2 * N_ * N_ * sizeof(u16);   // 16.78 MB
    const bool concurrent = ws_size >= 72 * MB + biasT_bytes;

    prep_kernel<<<8192, 256, 0, stream>>>(x, xs_h, xs_l, Wq, Wkv, Wo, wT_h, wT_l, woT_h, woT_l);

    if (concurrent) {
        u16* biasT = (u16*)(w + 72 * MB);   // disjoint: safe alongside gemm reads
        gemm_qkv_bias<<<2816, 256, 0, stream>>>(1, xs_h, xs_l, wT_h, wT_l,
                                                q_h, q_l, k_b, v_T, bias, mask, biasT);
        attn_kernel<<<dim3(32, 32), 256, 0, stream>>>(q_h, q_l, k_b, v_T, biasT, o_b);
    } else {
        u16* biasT = (u16*)(w + 32 * MB);   // aliases xs (dead after gemm) — sequential only
        gemm_qkv_bias<<<768, 256, 0, stream>>>(0, xs_h, xs_l, wT_h, wT_l,
                                               q_h, q_l, k_b, v_T, bias, mask, biasT);
        gemm_qkv_bias<<<2048, 256, 0, stream>>>(2, xs_h, xs_l, wT_h, wT_l,
                                                q_h, q_l, k_b, v_T, bias, mask, biasT);
        attn_kernel<<<dim3(32, 32), 256, 0, stream>>>(q_h, q_l, k_b, v_T, biasT, o_b);
    }
    gemm_out<<<dim3(16, 32), 256, 0, stream>>>(o_b, woT_h, woT_l, bo, out);
}